// Round 2
// baseline (53.736 us; speedup 1.0000x reference)
//
#include <hip/hip_runtime.h>

// BertWordEmbedder: B=64, T=512, H=768, W=256, D=256
// out[b,w,d] = (mean_{t: wid[b,t]==w} hs[b,t,:]) @ proj_w + proj_b
// word_ids sorted per row -> each 32-word group owns ONE contiguous token
// range. Phase A sweeps that range token-parallel (register accumulate,
// flush at word boundaries), Phase B is an MFMA GEMM vs pre-transposed W.

#define NB 64
#define NT 512
#define NH 768
#define NW 256
#define ND 256
#define WT 32            // words per block
#define PAD 8            // row stride 776 ushorts = 1552B -> no LDS bank conflicts
#define ROWE (NH + PAD)

typedef __attribute__((ext_vector_type(8))) short short8;       // 8 bf16 MFMA frag
typedef __attribute__((ext_vector_type(4))) float f32x4;        // MFMA C/D frag
typedef __attribute__((ext_vector_type(4))) float float4v;
typedef __attribute__((ext_vector_type(4))) unsigned short ushort4v;

__device__ __forceinline__ unsigned short f2bf(float f) {
    union { float f; unsigned u; } v; v.f = f;
    unsigned r = v.u + 0x7fffu + ((v.u >> 16) & 1u);  // RNE
    return (unsigned short)(r >> 16);
}

// Transpose + convert proj_w [H=768][D=256] fp32 -> Wt [D=256][H=768] bf16
__global__ void prep_wt(const float* __restrict__ w, unsigned short* __restrict__ wt) {
    __shared__ float tile[32][33];
    int tx = threadIdx.x & 31, ty = threadIdx.x >> 5;
    int k0 = blockIdx.x * 32, n0 = blockIdx.y * 32;
    #pragma unroll
    for (int i = 0; i < 4; ++i)
        tile[ty + 8 * i][tx] = w[(size_t)(k0 + ty + 8 * i) * ND + n0 + tx];
    __syncthreads();
    #pragma unroll
    for (int i = 0; i < 4; ++i)
        wt[(size_t)(n0 + ty + 8 * i) * NH + k0 + tx] = f2bf(tile[tx][ty + 8 * i]);
}

__global__ __launch_bounds__(256, 2)
void bert_pool_proj(const float* __restrict__ hs, const int* __restrict__ wid,
                    const unsigned short* __restrict__ wt, const float* __restrict__ bias,
                    float* __restrict__ out) {
    __shared__ int s_wid[NT + 1];
    __shared__ unsigned short s_pool[WT][ROWE];

    const int tid = threadIdx.x;
    const int b   = blockIdx.x >> 3;
    const int w0  = (blockIdx.x & 7) * WT;
    const int lane = tid & 63;
    const int wave = tid >> 6;

    // stage word ids + sentinel; zero the pool (empty words must stay 0)
    s_wid[tid]       = wid[b * NT + tid];
    s_wid[tid + 256] = wid[b * NT + tid + 256];
    if (tid == 0) s_wid[NT] = -1;
    {
        short8 z = {0, 0, 0, 0, 0, 0, 0, 0};
        int r = tid >> 3, c0 = (tid & 7) * 12;   // 8 threads/row, 12 chunks each
        #pragma unroll
        for (int j = 0; j < 12; ++j)
            *(short8*)&s_pool[r][(c0 + j) * 8] = z;
    }
    __syncthreads();

    // token range of this word group (redundant per-thread binary search)
    int t0, t1;
    {
        int lo = 0, hi = NT;
        while (lo < hi) { int m = (lo + hi) >> 1; if (s_wid[m] < w0) lo = m + 1; else hi = m; }
        t0 = lo;
        lo = 0; hi = NT;
        while (lo < hi) { int m = (lo + hi) >> 1; if (s_wid[m] < w0 + WT) lo = m + 1; else hi = m; }
        t1 = lo;
    }

    // ---- Phase A: token-parallel sweep, register accumulate, flush at word edges ----
    const bool act = tid < 192;                  // 192 threads x float4 = 768 floats
    const int  h   = (act ? tid : 0) * 4;
    const float* hb = hs + (size_t)b * NT * NH + h;

    float4v acc = {0.f, 0.f, 0.f, 0.f};
    int segs = t0;
    const float4v vz = {0.f, 0.f, 0.f, 0.f};

#define STEP(v, t) {                                                          \
        int cw = s_wid[(t)]; int nx = s_wid[(t) + 1];                         \
        acc[0] += (v)[0]; acc[1] += (v)[1]; acc[2] += (v)[2]; acc[3] += (v)[3]; \
        if (nx != cw) {                                                       \
            float sc = 1.0f / (float)((t) - segs + 1);                        \
            if (act) {                                                        \
                ushort4v u;                                                   \
                u[0] = f2bf(acc[0] * sc); u[1] = f2bf(acc[1] * sc);           \
                u[2] = f2bf(acc[2] * sc); u[3] = f2bf(acc[3] * sc);           \
                *(ushort4v*)&s_pool[cw - w0][h] = u;                          \
            }                                                                 \
            acc[0] = 0.f; acc[1] = 0.f; acc[2] = 0.f; acc[3] = 0.f;           \
            segs = (t) + 1;                                                   \
        }                                                                     \
    }

    int t = t0;
    for (; t + 4 <= t1; t += 4) {                // 4-deep load pipeline
        float4v v0 = act ? *(const float4v*)(hb + (size_t)(t    ) * NH) : vz;
        float4v v1 = act ? *(const float4v*)(hb + (size_t)(t + 1) * NH) : vz;
        float4v v2 = act ? *(const float4v*)(hb + (size_t)(t + 2) * NH) : vz;
        float4v v3 = act ? *(const float4v*)(hb + (size_t)(t + 3) * NH) : vz;
        STEP(v0, t); STEP(v1, t + 1); STEP(v2, t + 2); STEP(v3, t + 3);
    }
    for (; t < t1; ++t) {
        float4v v = act ? *(const float4v*)(hb + (size_t)t * NH) : vz;
        STEP(v, t);
    }
#undef STEP
    __syncthreads();

    // ---- Phase B: [32 x 768] x [768 x 256] MFMA GEMM (unchanged, verified) ----
    const int colg = wave * 64;
    const int cl   = lane & 15;
    const int kg   = lane >> 4;

    float bv[4];
    #pragma unroll
    for (int nt = 0; nt < 4; ++nt) bv[nt] = bias[colg + nt * 16 + cl];

    f32x4 acc2[2][4];
    #pragma unroll
    for (int mt = 0; mt < 2; ++mt)
        #pragma unroll
        for (int nt = 0; nt < 4; ++nt)
            #pragma unroll
            for (int r = 0; r < 4; ++r) acc2[mt][nt][r] = 0.f;

    for (int ks = 0; ks < NH / 32; ++ks) {
        const int kof = ks * 32 + kg * 8;
        short8 a0 = *(const short8*)&s_pool[cl][kof];
        short8 a1 = *(const short8*)&s_pool[16 + cl][kof];
        #pragma unroll
        for (int nt = 0; nt < 4; ++nt) {
            short8 bf = *(const short8*)&wt[(size_t)(colg + nt * 16 + cl) * NH + kof];
            acc2[0][nt] = __builtin_amdgcn_mfma_f32_16x16x32_bf16(a0, bf, acc2[0][nt], 0, 0, 0);
            acc2[1][nt] = __builtin_amdgcn_mfma_f32_16x16x32_bf16(a1, bf, acc2[1][nt], 0, 0, 0);
        }
    }

    #pragma unroll
    for (int mt = 0; mt < 2; ++mt)
        #pragma unroll
        for (int nt = 0; nt < 4; ++nt)
            #pragma unroll
            for (int r = 0; r < 4; ++r) {
                int wrow = w0 + mt * 16 + kg * 4 + r;
                out[((size_t)b * NW + wrow) * ND + colg + nt * 16 + cl] = acc2[mt][nt][r] + bv[nt];
            }
}

extern "C" void kernel_launch(void* const* d_in, const int* in_sizes, int n_in,
                              void* d_out, int out_size, void* d_ws, size_t ws_size,
                              hipStream_t stream) {
    const float* hs  = (const float*)d_in[0];
    const int*   wid = (const int*)d_in[1];
    const float* pw  = (const float*)d_in[2];
    const float* pb  = (const float*)d_in[3];
    float* out = (float*)d_out;
    unsigned short* wt = (unsigned short*)d_ws;   // 256*768*2 = 393216 B

    dim3 gp(NH / 32, ND / 32);
    prep_wt<<<gp, 256, 0, stream>>>(pw, wt);
    bert_pool_proj<<<NB * (NW / WT), 256, 0, stream>>>(hs, wid, wt, pb, out);
}